// Round 10
// baseline (50.363 us; speedup 1.0000x reference)
//
#include <hip/hip_runtime.h>
#include <hip/hip_bf16.h>
#include <stdint.h>

#define NB  256     // batch
#define NSP 128     // n_spins
#define DM  768     // d_model
#define KMC 25      // coalitions
#define MROWS (NB*KMC)  // 6400

// workspace layout (bytes), all 256-aligned (ws is 384 MiB)
#define OFF_S    0u          // s bf16 [6400][768]          9,830,400 B
#define OFF_WT   9830400u    // w_v^T bf16 [768][768]       1,179,648 B
#define OFF_N2   11010048u   // norm2 f32 [6400]               25,600 B
#define OFF_COEF 11035648u   // coefT f32 [128][28]            14,336 B
#define OFF_CB   11049984u   // Cb bf16 [32][128] (pad rows)    8,192 B

typedef __attribute__((ext_vector_type(8))) short bf16x8;
typedef __attribute__((ext_vector_type(4))) float f32x4;
typedef unsigned int u32;

#define GLOAD_LDS16(gp, lp) \
  __builtin_amdgcn_global_load_lds((const __attribute__((address_space(1))) u32*)(gp), \
                                   (__attribute__((address_space(3))) u32*)(lp), 16, 0, 0)

// counted-vmcnt barrier: wait until only the N newest VMEM ops remain in
// flight, then barrier. NEVER vmcnt(0) mid-loop -- deep DMA pipeline (T4).
#define KA_WAITV_BAR(N) asm volatile("s_waitcnt vmcnt(" #N ")\n\ts_barrier" ::: "memory")
// post-read barrier before a ring buffer is re-targeted by DMA
#define KA_BAR()        asm volatile("s_waitcnt lgkmcnt(0)\n\ts_barrier" ::: "memory")

// ---------------- prep: transpose w_v -> bf16 wT, coef/C tables, zero norm2 -
__global__ __launch_bounds__(256) void prep_kernel(const float* __restrict__ wv,
                                                   const int* __restrict__ co,
                                                   char* __restrict__ ws) {
  const int blk = blockIdx.x;
  const int t = threadIdx.x;
  if (blk < 144) {               // 12x12 tiles of 64x64: wT[n][k] = bf16(wv[k][n])
    __shared__ __hip_bfloat16 lt[64][66];
    const int bi = blk / 12, bj = blk % 12;
    const int k0 = bi * 64, n0 = bj * 64;
    #pragma unroll
    for (int i = 0; i < 16; ++i) {
      int idx = t + i * 256;
      int r = idx >> 6, c = idx & 63;
      lt[c][r] = __float2bfloat16(wv[(size_t)(k0 + r) * DM + n0 + c]);
    }
    __syncthreads();
    __hip_bfloat16* wT = (__hip_bfloat16*)(ws + OFF_WT);
    #pragma unroll
    for (int i = 0; i < 16; ++i) {
      int idx = t + i * 256;
      int r = idx >> 6, c = idx & 63;
      wT[(size_t)(n0 + r) * DM + k0 + c] = lt[r][c];
    }
  } else if (blk == 144) {       // per-(n,k) shapley coefficients
    if (t < NSP) {
      const int n = t;
      int cw = 0;
      #pragma unroll
      for (int k = 0; k < KMC; ++k) cw += co[k * NSP + n];
      const int cwo = KMC - cw;
      const bool valid = (cw > 0) && (cwo > 0);
      float* coefT = (float*)(ws + OFF_COEF);
      #pragma unroll
      for (int k = 0; k < 28; ++k) {
        float v = 0.f;
        if (valid && k < KMC) v = co[k * NSP + n] ? (1.f / (float)cw) : (-1.f / (float)cwo);
        coefT[n * 28 + k] = v;
      }
    }
  } else if (blk < 170) {        // zero norm2 accumulators
    int i = (blk - 145) * 256 + t;
    if (i < MROWS) ((float*)(ws + OFF_N2))[i] = 0.f;
  } else {                       // blk 170..201: Cb row k (bf16, rows>=KMC zero)
    int k = blk - 170;
    if (t < NSP) {
      float v = (k < KMC) ? (float)co[k * NSP + t] : 0.f;
      ((__hip_bfloat16*)(ws + OFF_CB))[k * NSP + t] = __float2bfloat16(v);
    }
  }
}

// ---------------- kernel A: s[b] = C(25x128) x F_b(128x768) via bf16 MFMA ---
// Latency-hiding-first design: F staged with global_load_lds (fire-and-forget
// DMA, no VGPR round-trip) into a 3-deep ring of f32 chunks [32][192] (24 KB
// each, 73.7 KB LDS -> 2 blocks/CU). Each wave keeps up to 18 DMA ops (18 KB)
// in flight; waits are counted vmcnt (12/12/6/0), never drain-0 mid-loop.
// 144 KB/CU in flight >> 53 KB needed to sustain HBM BW at ~900cy latency.
// f32->bf16 convert at LDS read (proven arithmetic, r5/r9). Grid 256b x 4sl.
__global__ __launch_bounds__(256, 2) void kA(const float* __restrict__ f,
                                             const __hip_bfloat16* __restrict__ Cb,
                                             __hip_bfloat16* __restrict__ s) {
  const int b = blockIdx.x;
  const int slice = blockIdx.y;    // 4 slices x 192 cols
  const int tid = threadIdx.x;
  const int w = tid >> 6;          // 4 waves
  const int lane = tid & 63;
  const int lo = lane & 15, hi = lane >> 4;

  __shared__ __align__(16) float Fs[3][32 * 192];   // 73,728 B ring

  // A-fragments (coalition rows), k = ks*32 + hi*8 + j (proven mapping)
  bf16x8 A0[4], A1[4];
  #pragma unroll
  for (int ks = 0; ks < 4; ++ks) {
    A0[ks] = *(const bf16x8*)(Cb + (size_t)lo * NSP + ks * 32 + hi * 8);
    A1[ks] = *(const bf16x8*)(Cb + (size_t)(16 + lo) * NSP + ks * 32 + hi * 8);
  }

  // DMA geometry: wave w stages windows w*6..w*6+5 (1024 B each) of a 24 KB
  // chunk. Per-lane GLOBAL source addr; LDS dest is wave-uniform (HW adds
  // lane*16). Window i covers float e = i*256 + lane*4 of [32][192]; 16 B
  // segments never cross a row (768 B rows, 16 B aligned).
  int goff[6];
  #pragma unroll
  for (int q = 0; q < 6; ++q) {
    int e = (w * 6 + q) * 256 + lane * 4;
    int r = e / 192, c = e - r * 192;
    goff[q] = r * DM + c;
  }

  const float* fb = f + (size_t)b * NSP * DM + slice * 192;

  f32x4 ac0[3], ac1[3];
  #pragma unroll
  for (int ct = 0; ct < 3; ++ct)
    #pragma unroll
    for (int i = 0; i < 4; ++i) { ac0[ct][i] = 0.f; ac1[ct][i] = 0.f; }

#define KA_ISSUE(ck, bi) { \
    const float* fp_ = fb + (size_t)(ck) * 32 * DM; \
    _Pragma("unroll") for (int q = 0; q < 6; ++q) \
      GLOAD_LDS16(fp_ + goff[q], (char*)&Fs[(bi)][0] + ((w * 6 + q) << 10)); }

#define KA_MFMA(ck, bi) { \
    _Pragma("unroll") for (int ct = 0; ct < 3; ++ct) { \
      bf16x8 Bf; \
      _Pragma("unroll") for (int j = 0; j < 8; ++j) { \
        float v_ = Fs[(bi)][(hi * 8 + j) * 192 + w * 48 + ct * 16 + lo]; \
        __hip_bfloat16 h_ = __float2bfloat16(v_); \
        Bf[j] = *(short*)&h_; } \
      ac0[ct] = __builtin_amdgcn_mfma_f32_16x16x32_bf16(A0[ck], Bf, ac0[ct], 0, 0, 0); \
      ac1[ct] = __builtin_amdgcn_mfma_f32_16x16x32_bf16(A1[ck], Bf, ac1[ct], 0, 0, 0); } }

  KA_ISSUE(0, 0)                 // 6 DMA/wave
  KA_ISSUE(1, 1)                 // 12
  KA_ISSUE(2, 2)                 // 18 in flight
  KA_WAITV_BAR(12);              // chunk0 landed (keep newest 12: c1,c2)
  KA_MFMA(0, 0)
  KA_BAR();                      // all waves done reading buf0 -> safe to re-DMA
  KA_ISSUE(3, 0)                 // back to <=18 in flight
  KA_WAITV_BAR(12);              // chunk1 landed (keep c2,c3)
  KA_MFMA(1, 1)
  KA_WAITV_BAR(6);               // chunk2 landed (keep c3)
  KA_MFMA(2, 2)
  KA_WAITV_BAR(0);               // chunk3 landed (epilogue: drain is fine)
  KA_MFMA(3, 0)

#undef KA_ISSUE
#undef KA_MFMA

  // epilogue: D layout col=lane&15, row=(lane>>4)*4+i
  #pragma unroll
  for (int ct = 0; ct < 3; ++ct) {
    int dcol = slice * 192 + w * 48 + ct * 16 + lo;
    #pragma unroll
    for (int i = 0; i < 4; ++i) {
      int r0 = hi * 4 + i;
      s[((size_t)b * KMC + r0) * DM + dcol] = __float2bfloat16(ac0[ct][i]);
      int r1 = 16 + hi * 4 + i;
      if (r1 < KMC)
        s[((size_t)b * KMC + r1) * DM + dcol] = __float2bfloat16(ac1[ct][i]);
    }
  }
}

// ---------------- kernel B: norm2[row] += rowwise |s @ wT^T|^2 (bf16 MFMA) ---
#define BM 128
#define BN 192
#define BK 32
#define NTK 24   // 768/32

__global__ __launch_bounds__(256) void kB(char* __restrict__ ws) {
  const int bid = blockIdx.x;      // grid 200 = 50 (M) * 4 (N)
  const int tm = bid >> 2;
  const int tn = bid & 3;
  const int tid = threadIdx.x;
  const int wid = tid >> 6;
  const int lane = tid & 63;
  const int wm = wid >> 1;         // 2x2 wave grid: 64 rows x 96 cols per wave
  const int wn = wid & 1;

  const __hip_bfloat16* S  = (const __hip_bfloat16*)(ws + OFF_S);
  const __hip_bfloat16* WT = (const __hip_bfloat16*)(ws + OFF_WT);
  float* norm2 = (float*)(ws + OFF_N2);

  __shared__ __align__(16) char As[2][BM * BK * 2];  // [128][32] bf16, 64B rows
  __shared__ __align__(16) char Bs[2][BN * BK * 2];  // [192][32] bf16, 64B rows

  // staging: global src pre-swizzled (slot ^= (r>>1)&3), LDS dest linear
  const char* gA[2]; char *lA0[2], *lA1[2];
  #pragma unroll
  for (int j = 0; j < 2; ++j) {
    int li = (wid * 2 + j) * 64 + lane;
    int r = li >> 2, sl = li & 3;
    int slx = sl ^ ((r >> 1) & 3);
    gA[j] = (const char*)(S + (size_t)(tm * BM + r) * DM) + slx * 16;
    lA0[j] = As[0] + (wid * 2 + j) * 1024;
    lA1[j] = As[1] + (wid * 2 + j) * 1024;
  }
  const char* gB[3]; char *lB0[3], *lB1[3];
  #pragma unroll
  for (int j = 0; j < 3; ++j) {
    int li = (wid * 3 + j) * 64 + lane;
    int r = li >> 2, sl = li & 3;
    int slx = sl ^ ((r >> 1) & 3);
    gB[j] = (const char*)(WT + (size_t)(tn * BN + r) * DM) + slx * 16;
    lB0[j] = Bs[0] + (wid * 3 + j) * 1024;
    lB1[j] = Bs[1] + (wid * 3 + j) * 1024;
  }

  auto stage = [&](int tk, int bsel) {
    size_t koff = (size_t)tk * (BK * 2);   // 64 bytes per K-step
    #pragma unroll
    for (int j = 0; j < 2; ++j) GLOAD_LDS16(gA[j] + koff, bsel ? lA1[j] : lA0[j]);
    #pragma unroll
    for (int j = 0; j < 3; ++j) GLOAD_LDS16(gB[j] + koff, bsel ? lB1[j] : lB0[j]);
  };

  f32x4 acc[4][6];
  #pragma unroll
  for (int m = 0; m < 4; ++m)
    #pragma unroll
    for (int n = 0; n < 6; ++n)
      #pragma unroll
      for (int j = 0; j < 4; ++j) acc[m][n][j] = 0.f;

  // fragment read offsets (swizzled to match stage-source permutation)
  int offA[4], offB[6];
  #pragma unroll
  for (int m = 0; m < 4; ++m) {
    int r = wm * 64 + m * 16 + (lane & 15);
    int sl = (lane >> 4) ^ ((r >> 1) & 3);
    offA[m] = r * 64 + sl * 16;
  }
  #pragma unroll
  for (int n = 0; n < 6; ++n) {
    int r = wn * 96 + n * 16 + (lane & 15);
    int sl = (lane >> 4) ^ ((r >> 1) & 3);
    offB[n] = r * 64 + sl * 16;
  }

  stage(0, 0);
  for (int tk = 0; tk < NTK; ++tk) {
    int cur = tk & 1;
    __syncthreads();               // drains vmcnt(0): staged tile ready
    if (tk + 1 < NTK) stage(tk + 1, cur ^ 1);
    bf16x8 af[4], bfr[6];
    #pragma unroll
    for (int m = 0; m < 4; ++m) af[m] = *(const bf16x8*)(As[cur] + offA[m]);
    #pragma unroll
    for (int n = 0; n < 6; ++n) bfr[n] = *(const bf16x8*)(Bs[cur] + offB[n]);
    #pragma unroll
    for (int m = 0; m < 4; ++m)
      #pragma unroll
      for (int n = 0; n < 6; ++n)
        acc[m][n] = __builtin_amdgcn_mfma_f32_16x16x32_bf16(af[m], bfr[n], acc[m][n], 0, 0, 0);
  }

  // epilogue: sum of squares over this block's 96-col slice, reduce 16 lanes,
  // atomicAdd into norm2[row]  (C/D layout: col=lane&15, row=(lane>>4)*4+reg)
  float ps[4][4];
  #pragma unroll
  for (int m = 0; m < 4; ++m)
    #pragma unroll
    for (int i = 0; i < 4; ++i) {
      float v = 0.f;
      #pragma unroll
      for (int n = 0; n < 6; ++n) { float x = acc[m][n][i]; v += x * x; }
      #pragma unroll
      for (int d = 1; d < 16; d <<= 1) v += __shfl_xor(v, d, 64);
      ps[m][i] = v;
    }
  if ((lane & 15) == 0) {
    int g = lane >> 4;
    #pragma unroll
    for (int m = 0; m < 4; ++m)
      #pragma unroll
      for (int i = 0; i < 4; ++i)
        atomicAdd(&norm2[tm * BM + wm * 64 + m * 16 + g * 4 + i], ps[m][i]);
  }
}

// ---------------- kernel C: cv = relu(sqrt(norm2)*scale); shapley ------------
__global__ __launch_bounds__(128) void kC(const char* __restrict__ ws,
                                          const float* __restrict__ scale,
                                          float* __restrict__ out) {
  const int b = blockIdx.x, n = threadIdx.x;
  const float* norm2 = (const float*)(ws + OFF_N2);
  const float* coefT = (const float*)(ws + OFF_COEF);
  __shared__ float cvs[32];
  if (n < KMC) {
    float nv = norm2[b * KMC + n];
    cvs[n] = fmaxf(sqrtf(fmaxf(nv, 0.f)) * scale[0], 0.f);
  } else if (n < 32) {
    cvs[n] = 0.f;
  }
  __syncthreads();
  float sum = 0.f;
  #pragma unroll
  for (int k = 0; k < KMC; ++k) sum += cvs[k] * coefT[n * 28 + k];
  out[b * NSP + n] = sum;
}

extern "C" void kernel_launch(void* const* d_in, const int* in_sizes, int n_in,
                              void* d_out, int out_size, void* d_ws, size_t ws_size,
                              hipStream_t stream) {
  const float* features   = (const float*)d_in[0];
  const int*   coalitions = (const int*)d_in[1];
  const float* wv         = (const float*)d_in[2];
  const float* scale      = (const float*)d_in[3];
  char* ws = (char*)d_ws;

  prep_kernel<<<202, 256, 0, stream>>>(wv, coalitions, ws);
  dim3 gaa(NB, 4);
  kA<<<gaa, 256, 0, stream>>>(features, (const __hip_bfloat16*)(ws + OFF_CB),
                              (__hip_bfloat16*)(ws + OFF_S));
  kB<<<200, 256, 0, stream>>>(ws);
  kC<<<NB, 128, 0, stream>>>(ws, scale, (float*)d_out);
}